// Round 1
// baseline (648.180 us; speedup 1.0000x reference)
//
#include <hip/hip_runtime.h>
#include <hip/hip_bf16.h>

#define D_MODEL 256
#define N_ROWS  262144      // B * FEATS_PER_IMAGE
#define N_Q     1024        // B * Q_PER_IMAGE
#define ROWS_PER_BATCH 65536

typedef __attribute__((ext_vector_type(8))) short short8;
typedef __attribute__((ext_vector_type(16))) float floatx16;

static __device__ __forceinline__ short f2bf(float x) {
    union { __hip_bfloat16 h; short s; } u;
    u.h = __float2bfloat16(x);
    return u.s;
}

// ---------------------------------------------------------------------------
// Kernel 1: 4-layer MLP on queries, fp32 compute, bf16 output to workspace.
// y = relu(x W^T + b) x3, then final linear. x: [1024, 256].
// Block = 256 threads handles 4 query rows; thread j computes output col j
// for all 4 rows (W row j stays in registers, LDS reads broadcast).
// ---------------------------------------------------------------------------
__global__ __launch_bounds__(256) void mlp_kernel(
    const float* __restrict__ q,
    const float* __restrict__ W1, const float* __restrict__ b1,
    const float* __restrict__ W2, const float* __restrict__ b2,
    const float* __restrict__ W3, const float* __restrict__ b3,
    const float* __restrict__ W4, const float* __restrict__ b4,
    __hip_bfloat16* __restrict__ xout)
{
    __shared__ float cur[4][D_MODEL];
    const int j = threadIdx.x;
    const int row0 = blockIdx.x * 4;

    #pragma unroll
    for (int i = 0; i < 4; i++)
        cur[i][j] = q[(long)(row0 + i) * D_MODEL + j];
    __syncthreads();

    const float* Ws[4] = { W1, W2, W3, W4 };
    const float* bs[4] = { b1, b2, b3, b4 };

    for (int l = 0; l < 4; l++) {
        const float4* wrow = (const float4*)(Ws[l] + (long)j * D_MODEL);
        float acc0 = bs[l][j];
        float acc1 = acc0, acc2 = acc0, acc3 = acc0;
        #pragma unroll 8
        for (int k = 0; k < D_MODEL / 4; k++) {
            float4 w  = wrow[k];
            float4 c0 = ((const float4*)cur[0])[k];
            float4 c1 = ((const float4*)cur[1])[k];
            float4 c2 = ((const float4*)cur[2])[k];
            float4 c3 = ((const float4*)cur[3])[k];
            acc0 += w.x*c0.x + w.y*c0.y + w.z*c0.z + w.w*c0.w;
            acc1 += w.x*c1.x + w.y*c1.y + w.z*c1.z + w.w*c1.w;
            acc2 += w.x*c2.x + w.y*c2.y + w.z*c2.z + w.w*c2.w;
            acc3 += w.x*c3.x + w.y*c3.y + w.z*c3.z + w.w*c3.w;
        }
        __syncthreads();
        if (l < 3) {
            cur[0][j] = fmaxf(acc0, 0.f);
            cur[1][j] = fmaxf(acc1, 0.f);
            cur[2][j] = fmaxf(acc2, 0.f);
            cur[3][j] = fmaxf(acc3, 0.f);
            __syncthreads();
        } else {
            xout[(long)(row0 + 0) * D_MODEL + j] = __float2bfloat16(acc0);
            xout[(long)(row0 + 1) * D_MODEL + j] = __float2bfloat16(acc1);
            xout[(long)(row0 + 2) * D_MODEL + j] = __float2bfloat16(acc2);
            xout[(long)(row0 + 3) * D_MODEL + j] = __float2bfloat16(acc3);
        }
    }
}

// ---------------------------------------------------------------------------
// Kernel 2: per-batch NT GEMM via bf16 MFMA, fp32 accumulate, direct-global.
// out[r][q] = dot(F[r,:], X[batch(r)*256 + q, :]),  r in [0, 262144), q in [0,256)
// Block = 4 waves = 64 rows x 256 cols. Wave tile 64x64 = 2x2 mfma_32x32x16.
// A (feats, fp32) loaded per-lane from global (L1 catches the 4-wave reuse),
// converted to bf16 in registers. B (bf16 MLP out) is L2-resident.
// No LDS, no barriers.
// ---------------------------------------------------------------------------
__global__ __launch_bounds__(256) void logits_kernel(
    const float* __restrict__ F,            // [262144, 256] fp32
    const __hip_bfloat16* __restrict__ X,   // [1024, 256] bf16
    float* __restrict__ out)                // [262144, 256] fp32
{
    const int wave = threadIdx.x >> 6;
    const int lane = threadIdx.x & 63;
    const int m    = lane & 31;     // row-in-32 (A) / col-in-32 (B)
    const int kg   = lane >> 5;     // k-group: k offset = kg*8

    const long row0  = (long)blockIdx.x * 64;       // first feature row of block
    const int  batch = (int)(row0 >> 16);           // 65536 rows per batch

    // A fragment bases: rows row0 + rt*32 + m, k offset kg*8 within each step
    const float* a0 = F + (row0 + m) * D_MODEL + kg * 8;
    const float* a1 = a0 + 32 * D_MODEL;

    // B fragment bases: X rows batch*256 + wave*64 + ct*32 + m
    const __hip_bfloat16* bb = X + ((long)(batch << 8) + (wave << 6) + m) * D_MODEL + kg * 8;
    const __hip_bfloat16* b0 = bb;
    const __hip_bfloat16* b1 = bb + 32 * D_MODEL;

    floatx16 acc00 = {0.f}, acc01 = {0.f}, acc10 = {0.f}, acc11 = {0.f};

    #pragma unroll 2
    for (int ks = 0; ks < 16; ks++) {
        const int k0 = ks * 16;   // 16 k per step

        float4 a0lo = *(const float4*)(a0 + k0);
        float4 a0hi = *(const float4*)(a0 + k0 + 4);
        float4 a1lo = *(const float4*)(a1 + k0);
        float4 a1hi = *(const float4*)(a1 + k0 + 4);

        short8 bf0 = *(const short8*)(b0 + k0);
        short8 bf1 = *(const short8*)(b1 + k0);

        short8 af0 = { f2bf(a0lo.x), f2bf(a0lo.y), f2bf(a0lo.z), f2bf(a0lo.w),
                       f2bf(a0hi.x), f2bf(a0hi.y), f2bf(a0hi.z), f2bf(a0hi.w) };
        short8 af1 = { f2bf(a1lo.x), f2bf(a1lo.y), f2bf(a1lo.z), f2bf(a1lo.w),
                       f2bf(a1hi.x), f2bf(a1hi.y), f2bf(a1hi.z), f2bf(a1hi.w) };

        acc00 = __builtin_amdgcn_mfma_f32_32x32x16_bf16(af0, bf0, acc00, 0, 0, 0);
        acc01 = __builtin_amdgcn_mfma_f32_32x32x16_bf16(af0, bf1, acc01, 0, 0, 0);
        acc10 = __builtin_amdgcn_mfma_f32_32x32x16_bf16(af1, bf0, acc10, 0, 0, 0);
        acc11 = __builtin_amdgcn_mfma_f32_32x32x16_bf16(af1, bf1, acc11, 0, 0, 0);
    }

    // C/D layout (verified m74/m101): col = lane&31, row = (reg&3) + 8*(reg>>2) + 4*(lane>>5)
    const int colbase = (wave << 6) + m;
    #pragma unroll
    for (int rt = 0; rt < 2; rt++) {
        const floatx16 accr0 = (rt == 0) ? acc00 : acc10;
        const floatx16 accr1 = (rt == 0) ? acc01 : acc11;
        const long rbase = row0 + rt * 32 + 4 * kg;
        #pragma unroll
        for (int reg = 0; reg < 16; reg++) {
            const int r = (reg & 3) + 8 * (reg >> 2);
            out[(rbase + r) * D_MODEL + colbase]      = accr0[reg];
            out[(rbase + r) * D_MODEL + colbase + 32] = accr1[reg];
        }
    }
}

extern "C" void kernel_launch(void* const* d_in, const int* in_sizes, int n_in,
                              void* d_out, int out_size, void* d_ws, size_t ws_size,
                              hipStream_t stream) {
    const float* queries = (const float*)d_in[0];
    const float* feats   = (const float*)d_in[1];
    // d_in[2] feature_indices, d_in[3] query_batch_offsets: not needed for values
    const float* W1 = (const float*)d_in[4];
    const float* b1 = (const float*)d_in[5];
    const float* W2 = (const float*)d_in[6];
    const float* b2 = (const float*)d_in[7];
    const float* W3 = (const float*)d_in[8];
    const float* b3 = (const float*)d_in[9];
    const float* W4 = (const float*)d_in[10];
    const float* b4 = (const float*)d_in[11];

    __hip_bfloat16* x_bf16 = (__hip_bfloat16*)d_ws;   // [1024, 256] bf16 = 512 KB

    mlp_kernel<<<N_Q / 4, 256, 0, stream>>>(queries, W1, b1, W2, b2, W3, b3, W4, b4, x_bf16);
    logits_kernel<<<N_ROWS / 64, 256, 0, stream>>>(feats, x_bf16, (float*)d_out);
}

// Round 2
// 553.043 us; speedup vs baseline: 1.1720x; 1.1720x over previous
//
#include <hip/hip_runtime.h>
#include <hip/hip_bf16.h>

#define D_MODEL 256
#define N_ROWS  262144      // B * FEATS_PER_IMAGE
#define N_Q     1024        // B * Q_PER_IMAGE

typedef __attribute__((ext_vector_type(8))) short short8;
typedef __attribute__((ext_vector_type(16))) float floatx16;

static __device__ __forceinline__ short f2bf(float x) {
    union { __hip_bfloat16 h; short s; } u;
    u.h = __float2bfloat16(x);
    return u.s;
}

// ---------------------------------------------------------------------------
// Kernel 1: 4-layer MLP on queries, fp32 compute, bf16 output to workspace.
// ---------------------------------------------------------------------------
__global__ __launch_bounds__(256) void mlp_kernel(
    const float* __restrict__ q,
    const float* __restrict__ W1, const float* __restrict__ b1,
    const float* __restrict__ W2, const float* __restrict__ b2,
    const float* __restrict__ W3, const float* __restrict__ b3,
    const float* __restrict__ W4, const float* __restrict__ b4,
    __hip_bfloat16* __restrict__ xout)
{
    __shared__ float cur[4][D_MODEL];
    const int j = threadIdx.x;
    const int row0 = blockIdx.x * 4;

    #pragma unroll
    for (int i = 0; i < 4; i++)
        cur[i][j] = q[(long)(row0 + i) * D_MODEL + j];
    __syncthreads();

    const float* Ws[4] = { W1, W2, W3, W4 };
    const float* bs[4] = { b1, b2, b3, b4 };

    for (int l = 0; l < 4; l++) {
        const float4* wrow = (const float4*)(Ws[l] + (long)j * D_MODEL);
        float acc0 = bs[l][j];
        float acc1 = acc0, acc2 = acc0, acc3 = acc0;
        #pragma unroll 8
        for (int k = 0; k < D_MODEL / 4; k++) {
            float4 w  = wrow[k];
            float4 c0 = ((const float4*)cur[0])[k];
            float4 c1 = ((const float4*)cur[1])[k];
            float4 c2 = ((const float4*)cur[2])[k];
            float4 c3 = ((const float4*)cur[3])[k];
            acc0 += w.x*c0.x + w.y*c0.y + w.z*c0.z + w.w*c0.w;
            acc1 += w.x*c1.x + w.y*c1.y + w.z*c1.z + w.w*c1.w;
            acc2 += w.x*c2.x + w.y*c2.y + w.z*c2.z + w.w*c2.w;
            acc3 += w.x*c3.x + w.y*c3.y + w.z*c3.z + w.w*c3.w;
        }
        __syncthreads();
        if (l < 3) {
            cur[0][j] = fmaxf(acc0, 0.f);
            cur[1][j] = fmaxf(acc1, 0.f);
            cur[2][j] = fmaxf(acc2, 0.f);
            cur[3][j] = fmaxf(acc3, 0.f);
            __syncthreads();
        } else {
            xout[(long)(row0 + 0) * D_MODEL + j] = __float2bfloat16(acc0);
            xout[(long)(row0 + 1) * D_MODEL + j] = __float2bfloat16(acc1);
            xout[(long)(row0 + 2) * D_MODEL + j] = __float2bfloat16(acc2);
            xout[(long)(row0 + 3) * D_MODEL + j] = __float2bfloat16(acc3);
        }
    }
}

// ---------------------------------------------------------------------------
// Kernel 2: per-batch NT GEMM, A staged coalesced through LDS as bf16.
// Block = 4 waves = 64 rows x 256 cols; wave tile 64x64 = 2x2 mfma_32x32x16.
// Stage: 64x256 fp32 A-tile loaded coalesced (16x dwordx4/thread burst),
// converted to bf16 once, stored to padded LDS (row stride 264 bf16 = 528 B:
// fragment ds_read_b128 covers all 32 banks per 8-lane phase).
// K=256 = one tile: stage -> barrier -> 16 k-steps -> store. No K-loop.
// Inter-block overlap (4 blocks/CU @ 33KB LDS) hides staging latency.
// ---------------------------------------------------------------------------
#define APAD 264

__global__ __launch_bounds__(256) void logits_kernel(
    const float* __restrict__ F,            // [262144, 256] fp32
    const __hip_bfloat16* __restrict__ X,   // [1024, 256] bf16
    float* __restrict__ out)                // [262144, 256] fp32
{
    __shared__ __hip_bfloat16 As[64 * APAD];   // 33792 B

    const int t    = threadIdx.x;
    const int wave = t >> 6;
    const int lane = t & 63;
    const int m    = lane & 31;     // row-in-32 (A) / col-in-32 (B)
    const int kg   = lane >> 5;     // k-group: k offset = kg*8

    const long row0  = (long)blockIdx.x * 64;
    const int  batch = (int)(row0 >> 16);       // 65536 rows per batch

    // ---- stage A tile: coalesced global fp32 -> bf16 LDS ----
    const float* Fbase = F + row0 * D_MODEL;
    #pragma unroll
    for (int i = 0; i < 16; i++) {
        const int flat = i * 256 + t;        // float4 index within 64x256 tile
        const int row  = flat >> 6;          // 64 float4 per row
        const int c4   = (flat & 63) << 2;   // float col
        float4 v = *(const float4*)(Fbase + (size_t)flat * 4);
        union { ushort4 u; short s[4]; } w;
        w.s[0] = f2bf(v.x); w.s[1] = f2bf(v.y);
        w.s[2] = f2bf(v.z); w.s[3] = f2bf(v.w);
        *(ushort4*)(&As[row * APAD + c4]) = w.u;   // 8B write, 2-way bank = free
    }
    __syncthreads();

    // ---- compute ----
    const __hip_bfloat16* a0 = &As[m * APAD + kg * 8];
    const __hip_bfloat16* a1 = a0 + 32 * APAD;
    const __hip_bfloat16* bb = X + ((long)(batch << 8) + (wave << 6) + m) * D_MODEL + kg * 8;
    const __hip_bfloat16* b0 = bb;
    const __hip_bfloat16* b1 = bb + 32 * D_MODEL;

    floatx16 acc00 = {0.f}, acc01 = {0.f}, acc10 = {0.f}, acc11 = {0.f};

    #pragma unroll 4
    for (int ks = 0; ks < 16; ks++) {
        const int k0 = ks * 16;   // 16 k per step; this lane covers k0+kg*8 .. +8

        short8 af0 = *(const short8*)(a0 + k0);   // ds_read_b128
        short8 af1 = *(const short8*)(a1 + k0);
        short8 bf0 = *(const short8*)(b0 + k0);   // global, L1/L2-hot
        short8 bf1 = *(const short8*)(b1 + k0);

        acc00 = __builtin_amdgcn_mfma_f32_32x32x16_bf16(af0, bf0, acc00, 0, 0, 0);
        acc01 = __builtin_amdgcn_mfma_f32_32x32x16_bf16(af0, bf1, acc01, 0, 0, 0);
        acc10 = __builtin_amdgcn_mfma_f32_32x32x16_bf16(af1, bf0, acc10, 0, 0, 0);
        acc11 = __builtin_amdgcn_mfma_f32_32x32x16_bf16(af1, bf1, acc11, 0, 0, 0);
    }

    // C/D layout (verified m74/m101): col = lane&31, row = (reg&3) + 8*(reg>>2) + 4*(lane>>5)
    const int colbase = (wave << 6) + m;
    #pragma unroll
    for (int rt = 0; rt < 2; rt++) {
        const floatx16 accr0 = (rt == 0) ? acc00 : acc10;
        const floatx16 accr1 = (rt == 0) ? acc01 : acc11;
        const long rbase = row0 + rt * 32 + 4 * kg;
        #pragma unroll
        for (int reg = 0; reg < 16; reg++) {
            const int r = (reg & 3) + 8 * (reg >> 2);
            out[(rbase + r) * D_MODEL + colbase]      = accr0[reg];
            out[(rbase + r) * D_MODEL + colbase + 32] = accr1[reg];
        }
    }
}

extern "C" void kernel_launch(void* const* d_in, const int* in_sizes, int n_in,
                              void* d_out, int out_size, void* d_ws, size_t ws_size,
                              hipStream_t stream) {
    const float* queries = (const float*)d_in[0];
    const float* feats   = (const float*)d_in[1];
    // d_in[2] feature_indices, d_in[3] query_batch_offsets: not needed for values
    const float* W1 = (const float*)d_in[4];
    const float* b1 = (const float*)d_in[5];
    const float* W2 = (const float*)d_in[6];
    const float* b2 = (const float*)d_in[7];
    const float* W3 = (const float*)d_in[8];
    const float* b3 = (const float*)d_in[9];
    const float* W4 = (const float*)d_in[10];
    const float* b4 = (const float*)d_in[11];

    __hip_bfloat16* x_bf16 = (__hip_bfloat16*)d_ws;   // [1024, 256] bf16 = 512 KB

    mlp_kernel<<<N_Q / 4, 256, 0, stream>>>(queries, W1, b1, W2, b2, W3, b3, W4, b4, x_bf16);
    logits_kernel<<<N_ROWS / 64, 256, 0, stream>>>(feats, x_bf16, (float*)d_out);
}